// Round 1
// baseline (363.769 us; speedup 1.0000x reference)
//
#include <hip/hip_runtime.h>

#define ENC 15
#define DIN 18
#define HID 128
#define RES 16

__global__ __launch_bounds__(256, 1)
void NSC_59133109732095_kernel(
    const float* __restrict__ points,     // [V,3]
    const float* __restrict__ encodings,  // [V,15]
    const float* __restrict__ W1,         // [128,18]
    const float* __restrict__ b1,         // [128]
    const float* __restrict__ W2,         // [128,128]
    const float* __restrict__ b2,         // [128]
    const float* __restrict__ W3,         // [3,128]
    const float* __restrict__ b3,         // [3]
    const int*   __restrict__ complexes,  // [C,4]
    float* __restrict__ out0,             // [C,16,16,3]  p + X
    float* __restrict__ out1,             // [C,16,16,3]  X
    float* __restrict__ out2)             // [1] lipschitz
{
    const int c   = blockIdx.x;
    const int tid = threadIdx.x;
    const int i   = tid >> 4;
    const int j   = tid & 15;

    // align_corners=True bilinear weights: u = linspace(0,1,16) = idx/15
    const float ui = (float)i * (1.0f / 15.0f);
    const float uj = (float)j * (1.0f / 15.0f);
    const float w00 = (1.0f - ui) * (1.0f - uj);
    const float w01 = (1.0f - ui) * uj;
    const float w10 = ui * (1.0f - uj);
    const float w11 = ui * uj;

    // corner vertex ids (wave-uniform -> scalar loads)
    const int v0 = complexes[c * 4 + 0];
    const int v1 = complexes[c * 4 + 1];
    const int v2 = complexes[c * 4 + 2];
    const int v3 = complexes[c * 4 + 3];

    // interpolated position p
    float p[3];
    #pragma unroll
    for (int f = 0; f < 3; ++f) {
        p[f] = w00 * points[v0 * 3 + f] + w01 * points[v1 * 3 + f]
             + w10 * points[v2 * 3 + f] + w11 * points[v3 * 3 + f];
    }

    // features X = [interp(enc) (15), sin(p) (3)]
    float X[DIN];
    #pragma unroll
    for (int k = 0; k < ENC; ++k) {
        X[k] = w00 * encodings[v0 * ENC + k] + w01 * encodings[v1 * ENC + k]
             + w10 * encodings[v2 * ENC + k] + w11 * encodings[v3 * ENC + k];
    }
    #pragma unroll
    for (int f = 0; f < 3; ++f) X[ENC + f] = __sinf(p[f]);

    // ---- Layer 1: 18 -> 128, sin. Fully unrolled so h1 stays in VGPRs. ----
    float h1[HID];
    #pragma unroll
    for (int jj = 0; jj < HID; ++jj) {
        float acc = b1[jj];
        #pragma unroll
        for (int k = 0; k < DIN; ++k)
            acc = fmaf(X[k], W1[jj * DIN + k], acc);
        h1[jj] = __sinf(acc);
    }

    // ---- Layer 2 (128 -> 128, sin) fused with Layer 3 (128 -> 3). ----
    float o0 = b3[0], o1 = b3[1], o2 = b3[2];
    #pragma unroll 1
    for (int jo = 0; jo < HID; jo += 4) {
        float a0 = b2[jo + 0];
        float a1 = b2[jo + 1];
        float a2 = b2[jo + 2];
        float a3 = b2[jo + 3];
        const float* __restrict__ w2r = W2 + jo * HID;
        #pragma unroll
        for (int k = 0; k < HID; ++k) {
            const float h = h1[k];
            a0 = fmaf(h, w2r[0 * HID + k], a0);
            a1 = fmaf(h, w2r[1 * HID + k], a1);
            a2 = fmaf(h, w2r[2 * HID + k], a2);
            a3 = fmaf(h, w2r[3 * HID + k], a3);
        }
        a0 = __sinf(a0);
        a1 = __sinf(a1);
        a2 = __sinf(a2);
        a3 = __sinf(a3);
        o0 = fmaf(a0, W3[0 * HID + jo + 0], o0);
        o0 = fmaf(a1, W3[0 * HID + jo + 1], o0);
        o0 = fmaf(a2, W3[0 * HID + jo + 2], o0);
        o0 = fmaf(a3, W3[0 * HID + jo + 3], o0);
        o1 = fmaf(a0, W3[1 * HID + jo + 0], o1);
        o1 = fmaf(a1, W3[1 * HID + jo + 1], o1);
        o1 = fmaf(a2, W3[1 * HID + jo + 2], o1);
        o1 = fmaf(a3, W3[1 * HID + jo + 3], o1);
        o2 = fmaf(a0, W3[2 * HID + jo + 0], o2);
        o2 = fmaf(a1, W3[2 * HID + jo + 1], o2);
        o2 = fmaf(a2, W3[2 * HID + jo + 2], o2);
        o2 = fmaf(a3, W3[2 * HID + jo + 3], o2);
    }

    // ---- outputs: out0 = p + X, out1 = X ----
    const int pix = c * (RES * RES) + tid;
    out0[pix * 3 + 0] = p[0] + o0;
    out0[pix * 3 + 1] = p[1] + o1;
    out0[pix * 3 + 2] = p[2] + o2;
    out1[pix * 3 + 0] = o0;
    out1[pix * 3 + 1] = o1;
    out1[pix * 3 + 2] = o2;

    if (c == 0 && tid == 0) out2[0] = 1.0f;
}

extern "C" void kernel_launch(void* const* d_in, const int* in_sizes, int n_in,
                              void* d_out, int out_size, void* d_ws, size_t ws_size,
                              hipStream_t stream) {
    const float* points    = (const float*)d_in[0];
    const float* encodings = (const float*)d_in[1];
    const float* W1        = (const float*)d_in[2];
    const float* b1        = (const float*)d_in[3];
    const float* W2        = (const float*)d_in[4];
    const float* b2        = (const float*)d_in[5];
    const float* W3        = (const float*)d_in[6];
    const float* b3        = (const float*)d_in[7];
    const int*   complexes = (const int*)d_in[8];
    // d_in[9] = resolution scalar (16), compile-time constant here

    const int C  = in_sizes[8] / 4;          // 2048
    const int N3 = C * RES * RES * 3;        // 1,572,864

    float* out0 = (float*)d_out;
    float* out1 = out0 + N3;
    float* out2 = out1 + N3;

    NSC_59133109732095_kernel<<<C, 256, 0, stream>>>(
        points, encodings, W1, b1, W2, b2, W3, b3, complexes,
        out0, out1, out2);
}

// Round 2
// 61.882 us; speedup vs baseline: 5.8784x; 5.8784x over previous
//
#include <hip/hip_runtime.h>
#include <hip/hip_bf16.h>

#define ENC 15
#define HID 128
#define RES 16

typedef __attribute__((ext_vector_type(4))) float f32x4;
typedef __attribute__((ext_vector_type(8))) short s16x8;
typedef __attribute__((ext_vector_type(4))) short s16x4;

static __device__ __forceinline__ short f2bf(float v) {
    __hip_bfloat16 h = __float2bfloat16(v);
    return __builtin_bit_cast(short, h);
}

// ---- weight prep: fp32 -> bf16 (zero-padded) into workspace ----
// ws layout (bf16 elements):
//   W1b [128][32]  @ 0      (k padded 18->32)
//   W2b [128][128] @ 4096
//   W3b [16][128]  @ 20480  (rows padded 3->16)
__global__ void NSC_prep_kernel(const float* __restrict__ W1,
                                const float* __restrict__ W2,
                                const float* __restrict__ W3,
                                __hip_bfloat16* __restrict__ ws) {
    int t = blockIdx.x * 256 + threadIdx.x;
    if (t < 4096) {
        int row = t >> 5, k = t & 31;
        float v = (k < 18) ? W1[row * 18 + k] : 0.0f;
        ws[t] = __float2bfloat16(v);
    } else if (t < 20480) {
        ws[t] = __float2bfloat16(W2[t - 4096]);
    } else if (t < 22528) {
        int i = t - 20480;
        int row = i >> 7, k = i & 127;
        float v = (row < 3) ? W3[row * 128 + k] : 0.0f;
        ws[t] = __float2bfloat16(v);
    }
}

// One block = one complex = 256 pixels (4 waves). All GEMMs swapped:
// C[feature][pixel] = W[feature][k] * H^T[k][pixel], mfma_f32_16x16x32_bf16.
// LDS: one 64 KB buffer, time-shared:
//   X phase : bf16 [256 px][32 k], row 64 B, swizzle  byte ^= (px&3)<<4
//   H phase : bf16 [256 px][128 f], row 256 B, swizzle byte ^= (px&7)<<4
//   outL    : float [256][5] at base (after H reads done)
__global__ __launch_bounds__(256, 2)
void NSC_59133109732095_kernel(
    const float* __restrict__ points,
    const float* __restrict__ encodings,
    const float* __restrict__ b1,
    const float* __restrict__ b2,
    const float* __restrict__ b3,
    const int*   __restrict__ complexes,
    const __hip_bfloat16* __restrict__ ws,
    float* __restrict__ out0,
    float* __restrict__ out1,
    float* __restrict__ out2)
{
    __shared__ __align__(16) char smem[65536];
    char*  Xb   = smem;           // [256][64 B]
    char*  Hb   = smem;           // [256][256 B]
    float* outL = (float*)smem;   // [256][5]

    const int c    = blockIdx.x;
    const int tid  = threadIdx.x;
    const int lane = tid & 63;
    const int wv   = tid >> 6;    // wave 0..3 -> pixels [wv*64, wv*64+64)
    const int g    = lane >> 4;   // k-group 0..3
    const int r16  = lane & 15;

    const __hip_bfloat16* W1b = ws;
    const __hip_bfloat16* W2b = ws + 4096;
    const __hip_bfloat16* W3b = ws + 20480;

    // ---- phase 0: per-thread bilinear interp, pixel = tid ----
    const int pi = tid >> 4, pj = tid & 15;
    const float ui = (float)pi * (1.0f / 15.0f);
    const float uj = (float)pj * (1.0f / 15.0f);
    const float w00 = (1.0f - ui) * (1.0f - uj), w01 = (1.0f - ui) * uj;
    const float w10 = ui * (1.0f - uj),          w11 = ui * uj;
    const int v0 = complexes[c * 4 + 0], v1 = complexes[c * 4 + 1];
    const int v2 = complexes[c * 4 + 2], v3 = complexes[c * 4 + 3];

    float p[3];
    #pragma unroll
    for (int f = 0; f < 3; ++f)
        p[f] = w00 * points[v0 * 3 + f] + w01 * points[v1 * 3 + f]
             + w10 * points[v2 * 3 + f] + w11 * points[v3 * 3 + f];

    float Xf[18];
    #pragma unroll
    for (int k = 0; k < ENC; ++k)
        Xf[k] = w00 * encodings[v0 * ENC + k] + w01 * encodings[v1 * ENC + k]
              + w10 * encodings[v2 * ENC + k] + w11 * encodings[v3 * ENC + k];
    #pragma unroll
    for (int f = 0; f < 3; ++f) Xf[ENC + f] = __sinf(p[f]);

    // write X row (32 bf16, zero-padded) with (px&3) swizzle
    #pragma unroll
    for (int t = 0; t < 4; ++t) {
        s16x8 v;
        #pragma unroll
        for (int i = 0; i < 8; ++i) {
            int k = t * 8 + i;
            v[i] = (k < 18) ? f2bf(Xf[k]) : (short)0;
        }
        *(s16x8*)(Xb + tid * 64 + ((t * 16) ^ ((tid & 3) << 4))) = v;
    }
    __syncthreads();   // A: X visible

    // ---- layer 1: [128 j] x [32 k] -> acc[j][px], bias-initialized ----
    f32x4 acc[8][4];
    #pragma unroll
    for (int m = 0; m < 8; ++m) {
        f32x4 bv = *(const f32x4*)(b1 + m * 16 + g * 4);
        #pragma unroll
        for (int n = 0; n < 4; ++n) acc[m][n] = bv;
    }
    {
        s16x8 a1[8];
        #pragma unroll
        for (int m = 0; m < 8; ++m)
            a1[m] = *(const s16x8*)(W1b + (m * 16 + r16) * 32 + g * 8);
        s16x8 bx[4];
        #pragma unroll
        for (int n = 0; n < 4; ++n) {
            int px = wv * 64 + n * 16 + r16;
            bx[n] = *(const s16x8*)(Xb + px * 64 + ((g * 16) ^ ((px & 3) << 4)));
        }
        #pragma unroll
        for (int m = 0; m < 8; ++m)
            #pragma unroll
            for (int n = 0; n < 4; ++n)
                acc[m][n] = __builtin_amdgcn_mfma_f32_16x16x32_bf16(a1[m], bx[n], acc[m][n], 0, 0, 0);
    }
    __syncthreads();   // B: X reads done, region may become H

    // sin -> bf16 -> H (h1), packed b64 per tile
    #pragma unroll
    for (int m = 0; m < 8; ++m)
        #pragma unroll
        for (int n = 0; n < 4; ++n) {
            s16x4 hv;
            #pragma unroll
            for (int r = 0; r < 4; ++r) hv[r] = f2bf(__sinf(acc[m][n][r]));
            int px = wv * 64 + n * 16 + r16;
            *(s16x4*)(Hb + px * 256 + ((m * 32 + g * 8) ^ ((px & 7) << 4))) = hv;
        }
    __syncthreads();   // C: h1 visible

    // ---- layer 2: [128 j] x [128 k] ----
    #pragma unroll
    for (int m = 0; m < 8; ++m) {
        f32x4 bv = *(const f32x4*)(b2 + m * 16 + g * 4);
        #pragma unroll
        for (int n = 0; n < 4; ++n) acc[m][n] = bv;
    }
    #pragma unroll
    for (int ks = 0; ks < 4; ++ks) {
        s16x8 a[8];
        #pragma unroll
        for (int m = 0; m < 8; ++m)
            a[m] = *(const s16x8*)(W2b + (m * 16 + r16) * 128 + ks * 32 + g * 8);
        s16x8 hb[4];
        #pragma unroll
        for (int n = 0; n < 4; ++n) {
            int px = wv * 64 + n * 16 + r16;
            hb[n] = *(const s16x8*)(Hb + px * 256 + ((ks * 64 + g * 16) ^ ((px & 7) << 4)));
        }
        #pragma unroll
        for (int m = 0; m < 8; ++m)
            #pragma unroll
            for (int n = 0; n < 4; ++n)
                acc[m][n] = __builtin_amdgcn_mfma_f32_16x16x32_bf16(a[m], hb[n], acc[m][n], 0, 0, 0);
    }
    __syncthreads();   // D: h1 reads done

    // sin -> bf16 -> H (h2 overwrites h1)
    #pragma unroll
    for (int m = 0; m < 8; ++m)
        #pragma unroll
        for (int n = 0; n < 4; ++n) {
            s16x4 hv;
            #pragma unroll
            for (int r = 0; r < 4; ++r) hv[r] = f2bf(__sinf(acc[m][n][r]));
            int px = wv * 64 + n * 16 + r16;
            *(s16x4*)(Hb + px * 256 + ((m * 32 + g * 8) ^ ((px & 7) << 4))) = hv;
        }
    __syncthreads();   // E: h2 visible

    // ---- layer 3: [16 j (3 used)] x [128 k] ----
    f32x4 acc3[4];
    #pragma unroll
    for (int n = 0; n < 4; ++n) acc3[n] = f32x4{0.f, 0.f, 0.f, 0.f};
    #pragma unroll
    for (int ks = 0; ks < 4; ++ks) {
        s16x8 a3 = *(const s16x8*)(W3b + r16 * 128 + ks * 32 + g * 8);
        #pragma unroll
        for (int n = 0; n < 4; ++n) {
            int px = wv * 64 + n * 16 + r16;
            s16x8 hb = *(const s16x8*)(Hb + px * 256 + ((ks * 64 + g * 16) ^ ((px & 7) << 4)));
            acc3[n] = __builtin_amdgcn_mfma_f32_16x16x32_bf16(a3, hb, acc3[n], 0, 0, 0);
        }
    }
    __syncthreads();   // F: h2 reads done, region may become outL

    if (g == 0) {      // lanes holding j = 0..3 (regs), j<3 valid
        #pragma unroll
        for (int n = 0; n < 4; ++n) {
            int px = wv * 64 + n * 16 + r16;
            outL[px * 5 + 0] = acc3[n][0];
            outL[px * 5 + 1] = acc3[n][1];
            outL[px * 5 + 2] = acc3[n][2];
        }
    }
    __syncthreads();   // G: outL visible

    // ---- epilogue: thread tid owns pixel tid ----
    float x0 = outL[tid * 5 + 0] + b3[0];
    float x1 = outL[tid * 5 + 1] + b3[1];
    float x2 = outL[tid * 5 + 2] + b3[2];
    const int base = c * 768 + tid * 3;
    out0[base + 0] = p[0] + x0;
    out0[base + 1] = p[1] + x1;
    out0[base + 2] = p[2] + x2;
    out1[base + 0] = x0;
    out1[base + 1] = x1;
    out1[base + 2] = x2;
    if (c == 0 && tid == 0) out2[0] = 1.0f;
}

extern "C" void kernel_launch(void* const* d_in, const int* in_sizes, int n_in,
                              void* d_out, int out_size, void* d_ws, size_t ws_size,
                              hipStream_t stream) {
    const float* points    = (const float*)d_in[0];
    const float* encodings = (const float*)d_in[1];
    const float* W1        = (const float*)d_in[2];
    const float* b1        = (const float*)d_in[3];
    const float* W2        = (const float*)d_in[4];
    const float* b2        = (const float*)d_in[5];
    const float* W3        = (const float*)d_in[6];
    const float* b3        = (const float*)d_in[7];
    const int*   complexes = (const int*)d_in[8];

    const int C  = in_sizes[8] / 4;          // 2048
    const int N3 = C * RES * RES * 3;        // 1,572,864

    float* out0 = (float*)d_out;
    float* out1 = out0 + N3;
    float* out2 = out1 + N3;

    __hip_bfloat16* ws = (__hip_bfloat16*)d_ws;  // needs 45056 B

    NSC_prep_kernel<<<88, 256, 0, stream>>>(W1, W2, W3, ws);
    NSC_59133109732095_kernel<<<C, 256, 0, stream>>>(
        points, encodings, b1, b2, b3, complexes, ws, out0, out1, out2);
}